// Round 1
// baseline (510.753 us; speedup 1.0000x reference)
//
#include <hip/hip_runtime.h>

// ---------- common ----------
typedef short bf16x8 __attribute__((ext_vector_type(8)));
typedef float f32x4  __attribute__((ext_vector_type(4)));

__device__ __forceinline__ unsigned short f2bf(float x) {
    unsigned int u = __float_as_uint(x);
    unsigned int r = (u + 0x7FFFu + ((u >> 16) & 1u)) >> 16;
    return (unsigned short)r;
}
__device__ __forceinline__ float bf2f(unsigned short b) {
    return __uint_as_float(((unsigned int)b) << 16);
}

#define P_TOT 6400          // B*N
#define DIM   2048
#define NRH   16
#define DKK   64
#define DVV   128
#define NSEQ  100
#define NB    64
#define GROWS 640000        // B*N*N

// ---------- kernel 1: cast a_features fp32 -> bf16 ----------
__global__ void k_cvt_a(const float* __restrict__ a, unsigned short* __restrict__ o, int n4) {
    int i = blockIdx.x * 256 + threadIdx.x;
    if (i < n4) {
        float4 v = ((const float4*)a)[i];
        ushort4 u;
        u.x = f2bf(v.x); u.y = f2bf(v.y); u.z = f2bf(v.z); u.w = f2bf(v.w);
        ((ushort4*)o)[i] = u;
    }
}

// ---------- kernel 2: transpose W[2048][1024] -> Wt[1024][2048] bf16 (z: K/Q) ----------
__global__ void k_tw(const float* __restrict__ Wk, const float* __restrict__ Wq,
                     unsigned short* __restrict__ Wt) {
    __shared__ float t[32][33];
    const float* W = blockIdx.z ? Wq : Wk;
    unsigned short* out = Wt + (size_t)blockIdx.z * 1024 * 2048;
    int n0 = blockIdx.x * 32, k0 = blockIdx.y * 32;
    int tx = threadIdx.x & 31, ty = threadIdx.x >> 5;   // 32 x 8
#pragma unroll
    for (int r = 0; r < 32; r += 8)
        t[ty + r][tx] = W[(size_t)(k0 + ty + r) * 1024 + n0 + tx];
    __syncthreads();
#pragma unroll
    for (int r = 0; r < 32; r += 8)
        out[(size_t)(n0 + ty + r) * 2048 + k0 + tx] = f2bf(t[tx][ty + r]);
}

// ---------- kernel 3: gate GEMM + log, output lg[h][row] bf16 ----------
// 4 lanes per row (fully coalesced g reads), shfl_xor reduce.
__global__ void k_gate(const float* __restrict__ g, const float* __restrict__ Wg,
                       const float* __restrict__ bg, unsigned short* __restrict__ lg) {
    __shared__ float wg[64 * 16];
    __shared__ float bgs[16];
    int tid = threadIdx.x;
    if (tid < 16) bgs[tid] = bg[tid];
    for (int i = tid; i < 1024; i += 256) wg[i] = Wg[i];
    __syncthreads();

    int row = blockIdx.x * 64 + (tid >> 2);
    int q   = tid & 3;                       // quarter of the 64-dim input
    const float4* gp = (const float4*)(g + (size_t)row * 64 + q * 16);

    float acc[16];
#pragma unroll
    for (int h = 0; h < 16; h++) acc[h] = 0.f;
#pragma unroll
    for (int c4 = 0; c4 < 4; c4++) {
        float4 gv = gp[c4];
        int cb = (q * 16 + c4 * 4) * 16;
#pragma unroll
        for (int h = 0; h < 16; h++) acc[h] += gv.x * wg[cb + h];
#pragma unroll
        for (int h = 0; h < 16; h++) acc[h] += gv.y * wg[cb + 16 + h];
#pragma unroll
        for (int h = 0; h < 16; h++) acc[h] += gv.z * wg[cb + 32 + h];
#pragma unroll
        for (int h = 0; h < 16; h++) acc[h] += gv.w * wg[cb + 48 + h];
    }
#pragma unroll
    for (int h = 0; h < 16; h++) {
        acc[h] += __shfl_xor(acc[h], 1);
        acc[h] += __shfl_xor(acc[h], 2);
    }
    if (q == 0) {
#pragma unroll
        for (int h = 0; h < 16; h++) {
            float v = fmaxf(acc[h] + bgs[h], 1e-6f);
            lg[(size_t)h * GROWS + row] = f2bf(__logf(v));
        }
    }
}

// ---------- kernel 4: C_bf16[6400][1024] = A_bf[6400][2048] @ Wt[n][k]^T + bias ----------
// 128x128 tile, 4 waves in 2x2, each wave 4x4 of 16x16x32 MFMA. LDS stride 40 (pad).
__global__ __launch_bounds__(256) void k_gemm(const unsigned short* __restrict__ A,
                                              const unsigned short* __restrict__ Wt,
                                              const float* __restrict__ bK,
                                              const float* __restrict__ bQ,
                                              unsigned short* __restrict__ out) {
    __shared__ unsigned short As[128 * 40];
    __shared__ unsigned short Bs[128 * 40];
    const unsigned short* Wz = Wt + (size_t)blockIdx.z * 1024 * 2048;
    const float* bias = blockIdx.z ? bQ : bK;
    unsigned short* oz = out + (size_t)blockIdx.z * P_TOT * 1024;
    int mBase = blockIdx.y * 128, nBase = blockIdx.x * 128;
    int tid = threadIdx.x;
    int lane = tid & 63, w = tid >> 6;
    int wm = w >> 1, wn = w & 1;
    int l15 = lane & 15, q = lane >> 4;

    f32x4 zero4 = {0.f, 0.f, 0.f, 0.f};
    f32x4 acc[4][4];
#pragma unroll
    for (int i = 0; i < 4; i++)
#pragma unroll
        for (int j = 0; j < 4; j++) acc[i][j] = zero4;

    int srow = tid >> 1, sc = tid & 1;           // each thread: 1 row, chunks sc & sc+2
    const unsigned short* aRow = A  + (size_t)(mBase + srow) * 2048 + sc * 8;
    const unsigned short* bRow = Wz + (size_t)(nBase + srow) * 2048 + sc * 8;

    for (int kt = 0; kt < 64; kt++) {
        int kk = kt * 32;
        __syncthreads();
        uint4 av0 = *(const uint4*)(aRow + kk);
        uint4 av1 = *(const uint4*)(aRow + kk + 16);
        uint4 bv0 = *(const uint4*)(bRow + kk);
        uint4 bv1 = *(const uint4*)(bRow + kk + 16);
        *(uint4*)(&As[srow * 40 + sc * 8])      = av0;
        *(uint4*)(&As[srow * 40 + sc * 8 + 16]) = av1;
        *(uint4*)(&Bs[srow * 40 + sc * 8])      = bv0;
        *(uint4*)(&Bs[srow * 40 + sc * 8 + 16]) = bv1;
        __syncthreads();

        bf16x8 aF[4], bF[4];
#pragma unroll
        for (int mt = 0; mt < 4; mt++)
            aF[mt] = *(const bf16x8*)(&As[(wm * 64 + mt * 16 + l15) * 40 + q * 8]);
#pragma unroll
        for (int nt = 0; nt < 4; nt++)
            bF[nt] = *(const bf16x8*)(&Bs[(wn * 64 + nt * 16 + l15) * 40 + q * 8]);
#pragma unroll
        for (int mt = 0; mt < 4; mt++)
#pragma unroll
            for (int nt = 0; nt < 4; nt++)
                acc[mt][nt] = __builtin_amdgcn_mfma_f32_16x16x32_bf16(aF[mt], bF[nt], acc[mt][nt], 0, 0, 0);
    }
#pragma unroll
    for (int nt = 0; nt < 4; nt++) {
        int n = nBase + wn * 64 + nt * 16 + l15;
        float bv = bias[n];
#pragma unroll
        for (int mt = 0; mt < 4; mt++)
#pragma unroll
            for (int r = 0; r < 4; r++) {
                int m = mBase + wm * 64 + mt * 16 + q * 4 + r;
                oz[(size_t)m * 1024 + n] = f2bf(acc[mt][nt][r] + bv);
            }
    }
}

// ---------- kernel 5: fused attention per (b,h) ----------
// LDS: region1 = Ks(112x72)+Qs(112x72) bf16, later overlaid by finT(112x136) bf16
//      region2 = S (100x104) bf16.  Total 53,056 B.
__global__ __launch_bounds__(256) void k_attn(const unsigned short* __restrict__ kq,
                                              const unsigned short* __restrict__ abf,
                                              const unsigned short* __restrict__ lg,
                                              const float* __restrict__ wsp,
                                              const float* __restrict__ bsp,
                                              float* __restrict__ out) {
    __shared__ unsigned short sh[2 * 112 * 72 + 100 * 104];
    unsigned short* Ks = sh;
    unsigned short* Qs = sh + 112 * 72;
    unsigned short* fT = sh;                 // overlays Ks/Qs after S phase
    unsigned short* Sb = sh + 2 * 112 * 72;

    int h = blockIdx.x, b = blockIdx.y;
    int tid = threadIdx.x, lane = tid & 63, w = tid >> 6;
    int l15 = lane & 15, q = lane >> 4;

    // ---- stage K,Q (bf16, 100x64 each) ----
    const unsigned short* Kg = kq + (size_t)(b * NSEQ) * 1024 + h * 64;
    const unsigned short* Qg = kq + (size_t)P_TOT * 1024 + (size_t)(b * NSEQ) * 1024 + h * 64;
    for (int c = tid; c < 800; c += 256) {
        int row = c >> 3, off = (c & 7) * 8;
        *(uint4*)(&Ks[row * 72 + off]) = *(const uint4*)(Kg + (size_t)row * 1024 + off);
        *(uint4*)(&Qs[row * 72 + off]) = *(const uint4*)(Qg + (size_t)row * 1024 + off);
    }
    __syncthreads();

    // ---- S = K Q^T / 8 + log-gate  (MFMA, 7x7 tiles over 4 waves) ----
    const unsigned short* lgh = lg + (size_t)h * GROWS + (size_t)b * NSEQ * NSEQ;
    for (int p = w; p < 49; p += 4) {
        int mt = p / 7, nt = p % 7;
        bf16x8 a0 = *(const bf16x8*)(&Ks[(mt * 16 + l15) * 72 + q * 8]);
        bf16x8 a1 = *(const bf16x8*)(&Ks[(mt * 16 + l15) * 72 + 32 + q * 8]);
        bf16x8 b0 = *(const bf16x8*)(&Qs[(nt * 16 + l15) * 72 + q * 8]);
        bf16x8 b1 = *(const bf16x8*)(&Qs[(nt * 16 + l15) * 72 + 32 + q * 8]);
        f32x4 c = {0.f, 0.f, 0.f, 0.f};
        c = __builtin_amdgcn_mfma_f32_16x16x32_bf16(a0, b0, c, 0, 0, 0);
        c = __builtin_amdgcn_mfma_f32_16x16x32_bf16(a1, b1, c, 0, 0, 0);
        int j = nt * 16 + l15;
        if (j < NSEQ) {
#pragma unroll
            for (int r = 0; r < 4; r++) {
                int i = mt * 16 + q * 4 + r;
                if (i < NSEQ) {
                    float lv = bf2f(lgh[i * NSEQ + j]);
                    Sb[i * 104 + j] = f2bf(c[r] * 0.125f + lv);
                }
            }
        }
    }
    __syncthreads();

    // ---- column softmax over i; write finT[j][i] bf16, zero-padded i in [100,128) ----
    if (tid < 112) {
        int j = tid;
        if (j < NSEQ) {
            float mx = -1e30f;
            for (int i = 0; i < NSEQ; i++) mx = fmaxf(mx, bf2f(Sb[i * 104 + j]));
            float sum = 0.f;
            for (int i = 0; i < NSEQ; i++) sum += __expf(bf2f(Sb[i * 104 + j]) - mx);
            float inv = 1.f / sum;
            for (int i = 0; i < NSEQ; i++)
                fT[j * 136 + i] = f2bf(__expf(bf2f(Sb[i * 104 + j]) - mx) * inv);
            for (int i = NSEQ; i < 128; i++) fT[j * 136 + i] = 0;
        } else {
            for (int i = 0; i < 128; i++) fT[j * 136 + i] = 0;
        }
    }
    __syncthreads();

    // ---- R = finT @ V  (V gathered bf16 from global a); out = R*w_s + b_s ----
    float wsv = wsp[0], bsv = bsp[0];
    const unsigned short* Vg = abf + (size_t)(b * NSEQ) * 2048 + h * 128;
    for (int nt2 = 0; nt2 < 2; nt2++) {
        int nt = w * 2 + nt2;
        int d = nt * 16 + l15;
        bf16x8 bF[4];
#pragma unroll
        for (int ks = 0; ks < 4; ks++) {
            bf16x8 f;
#pragma unroll
            for (int jj = 0; jj < 8; jj++) {
                int i = ks * 32 + q * 8 + jj;
                unsigned short v = (i < NSEQ) ? Vg[(size_t)i * 2048 + d] : (unsigned short)0;
                f[jj] = (short)v;
            }
            bF[ks] = f;
        }
        for (int mt = 0; mt < 7; mt++) {
            f32x4 c = {0.f, 0.f, 0.f, 0.f};
#pragma unroll
            for (int ks = 0; ks < 4; ks++) {
                bf16x8 aF = *(const bf16x8*)(&fT[(mt * 16 + l15) * 136 + ks * 32 + q * 8]);
                c = __builtin_amdgcn_mfma_f32_16x16x32_bf16(aF, bF[ks], c, 0, 0, 0);
            }
#pragma unroll
            for (int r = 0; r < 4; r++) {
                int j = mt * 16 + q * 4 + r;
                if (j < NSEQ)
                    out[(size_t)(b * NSEQ + j) * 2048 + h * 128 + d] = c[r] * wsv + bsv;
            }
        }
    }
}

// ---------- launch ----------
extern "C" void kernel_launch(void* const* d_in, const int* in_sizes, int n_in,
                              void* d_out, int out_size, void* d_ws, size_t ws_size,
                              hipStream_t stream) {
    const float* a  = (const float*)d_in[0];
    const float* g  = (const float*)d_in[1];
    const float* Wg = (const float*)d_in[4];
    const float* bg = (const float*)d_in[5];
    const float* WK = (const float*)d_in[6];
    const float* bK = (const float*)d_in[7];
    const float* WQ = (const float*)d_in[8];
    const float* bQ = (const float*)d_in[9];
    const float* ws_s = (const float*)d_in[10];
    const float* bs_s = (const float*)d_in[11];
    float* out = (float*)d_out;

    // workspace layout (bytes)
    const size_t off_abf = 0;                        // 6400*2048*2      = 26,214,400
    const size_t off_wt  = off_abf + 26214400;       // 2*1024*2048*2   =  8,388,608
    const size_t off_kq  = off_wt + 8388608;         // 2*6400*1024*2   = 26,214,400
    const size_t off_lg  = off_kq + 26214400;        // 16*640000*2     = 20,480,000
    const size_t need    = off_lg + 20480000;        // 81,297,408
    if (ws_size < need) return;                      // visible failure instead of OOB

    char* ws = (char*)d_ws;
    unsigned short* a_bf = (unsigned short*)(ws + off_abf);
    unsigned short* Wt   = (unsigned short*)(ws + off_wt);
    unsigned short* kq   = (unsigned short*)(ws + off_kq);
    unsigned short* lg   = (unsigned short*)(ws + off_lg);

    k_cvt_a<<<12800, 256, 0, stream>>>(a, a_bf, 3276800);
    k_tw<<<dim3(32, 64, 2), 256, 0, stream>>>(WK, WQ, Wt);
    k_gate<<<10000, 256, 0, stream>>>(g, Wg, bg, lg);
    k_gemm<<<dim3(8, 50, 2), 256, 0, stream>>>(a_bf, Wt, bK, bQ, kq);
    k_attn<<<dim3(16, 64), 256, 0, stream>>>(kq, a_bf, lg, ws_s, bs_s, out);
}

// Round 2
// 455.518 us; speedup vs baseline: 1.1213x; 1.1213x over previous
//
#include <hip/hip_runtime.h>

// ---------- common ----------
typedef short bf16x8 __attribute__((ext_vector_type(8)));
typedef float f32x4  __attribute__((ext_vector_type(4)));

__device__ __forceinline__ unsigned short f2bf(float x) {
    unsigned int u = __float_as_uint(x);
    unsigned int r = (u + 0x7FFFu + ((u >> 16) & 1u)) >> 16;
    return (unsigned short)r;
}
__device__ __forceinline__ float bf2f(unsigned short b) {
    return __uint_as_float(((unsigned int)b) << 16);
}

typedef __attribute__((address_space(1))) const void* as1_cvp;
typedef __attribute__((address_space(3))) void* as3_vp;
__device__ __forceinline__ void cp16(const void* g, void* l) {
    // async global->LDS DMA, 16B per lane; LDS dst = wave-uniform base + lane*16
    __builtin_amdgcn_global_load_lds((as1_cvp)g, (as3_vp)l, 16, 0, 0);
}

#define P_TOT 6400          // B*N
#define NRH   16
#define NSEQ  100
#define GROWS 640000        // B*N*N

// ---------- kernel 1: cast a_features fp32 -> bf16 ----------
__global__ void k_cvt_a(const float* __restrict__ a, unsigned short* __restrict__ o, int n4) {
    int i = blockIdx.x * 256 + threadIdx.x;
    if (i < n4) {
        float4 v = ((const float4*)a)[i];
        ushort4 u;
        u.x = f2bf(v.x); u.y = f2bf(v.y); u.z = f2bf(v.z); u.w = f2bf(v.w);
        ((ushort4*)o)[i] = u;
    }
}

// ---------- kernel 2: transpose W[2048][1024] -> Wt rows n (z=0:K cols, z=1:Q cols) ----------
__global__ void k_tw(const float* __restrict__ Wk, const float* __restrict__ Wq,
                     unsigned short* __restrict__ Wt) {
    __shared__ float t[32][33];
    const float* W = blockIdx.z ? Wq : Wk;
    unsigned short* out = Wt + (size_t)blockIdx.z * 1024 * 2048;
    int n0 = blockIdx.x * 32, k0 = blockIdx.y * 32;
    int tx = threadIdx.x & 31, ty = threadIdx.x >> 5;   // 32 x 8
#pragma unroll
    for (int r = 0; r < 32; r += 8)
        t[ty + r][tx] = W[(size_t)(k0 + ty + r) * 1024 + n0 + tx];
    __syncthreads();
#pragma unroll
    for (int r = 0; r < 32; r += 8)
        out[(size_t)(n0 + ty + r) * 2048 + k0 + tx] = f2bf(t[tx][ty + r]);
}

// ---------- kernel 3: gate GEMM + log -> lg[h][b*N*N + i*N + j] bf16 ----------
// 4 lanes per row; wg stride 17 (q-groups land 16 banks apart -> 2-way, free).
__global__ void k_gate(const float* __restrict__ g, const float* __restrict__ Wg,
                       const float* __restrict__ bg, unsigned short* __restrict__ lg) {
    __shared__ float wg[64 * 17];
    __shared__ float bgs[16];
    int tid = threadIdx.x;
    if (tid < 16) bgs[tid] = bg[tid];
    for (int i = tid; i < 1024; i += 256) {
        int c = i >> 4, hh = i & 15;
        wg[c * 17 + hh] = Wg[i];
    }
    __syncthreads();

    int row = blockIdx.x * 64 + (tid >> 2);
    int q   = tid & 3;                       // quarter of the 64-dim input
    const float4* gp = (const float4*)(g + (size_t)row * 64 + q * 16);

    float acc[16];
#pragma unroll
    for (int h = 0; h < 16; h++) acc[h] = 0.f;
#pragma unroll
    for (int c4 = 0; c4 < 4; c4++) {
        float4 gv = gp[c4];
        int cb = q * 16 + c4 * 4;
#pragma unroll
        for (int h = 0; h < 16; h++) acc[h] += gv.x * wg[(cb + 0) * 17 + h];
#pragma unroll
        for (int h = 0; h < 16; h++) acc[h] += gv.y * wg[(cb + 1) * 17 + h];
#pragma unroll
        for (int h = 0; h < 16; h++) acc[h] += gv.z * wg[(cb + 2) * 17 + h];
#pragma unroll
        for (int h = 0; h < 16; h++) acc[h] += gv.w * wg[(cb + 3) * 17 + h];
    }
#pragma unroll
    for (int h = 0; h < 16; h++) {
        acc[h] += __shfl_xor(acc[h], 1);
        acc[h] += __shfl_xor(acc[h], 2);
    }
    // every lane holds full sums; lane q stores h = 4q..4q+3
#pragma unroll
    for (int u = 0; u < 4; u++) {
        int h = q * 4 + u;
        float v = fmaxf(acc[h] + bgs[h], 1e-6f);
        lg[(size_t)h * GROWS + row] = f2bf(__logf(v));
    }
}

// ---------- kernel 4: kq2[6400][2048] = A_bf[6400][2048] @ Wt^T + bias (m97-style) ----------
// 128x128 tile, BK=32, global_load_lds width-16, XCD swizzle on m.
__global__ __launch_bounds__(256) void k_gemm(const unsigned short* __restrict__ A,
                                              const unsigned short* __restrict__ Wt,
                                              const float* __restrict__ bK,
                                              const float* __restrict__ bQ,
                                              unsigned short* __restrict__ out) {
    __shared__ unsigned short As[128 * 32];
    __shared__ unsigned short Bs[128 * 32];
    // swizzle: blocks sharing an A-slice (same m) land on one XCD (lid%8 == m%8)
    int lid = blockIdx.x;
    int mb, nb;
    if (lid < 768) { int gg = lid >> 7, r = lid & 127; nb = r >> 3; mb = gg * 8 + (r & 7); }
    else           { int r = lid - 768; nb = r >> 1; mb = 48 + (r & 1); }
    int mBase = mb * 128, nBase = nb * 128;
    int tid = threadIdx.x, lane = tid & 63, w = tid >> 6;
    int wm = w >> 1, wn = w & 1, l15 = lane & 15, q = lane >> 4;

    // staging: chunk c (16B) of the 128x32 tile; wave w covers chunks [w*128, w*128+128)
    int c0 = w * 128 + lane, c1 = c0 + 64;
    const unsigned short* gA0 = A  + (size_t)(mBase + (c0 >> 2)) * 2048 + (c0 & 3) * 8;
    const unsigned short* gA1 = A  + (size_t)(mBase + (c1 >> 2)) * 2048 + (c1 & 3) * 8;
    const unsigned short* gB0 = Wt + (size_t)(nBase + (c0 >> 2)) * 2048 + (c0 & 3) * 8;
    const unsigned short* gB1 = Wt + (size_t)(nBase + (c1 >> 2)) * 2048 + (c1 & 3) * 8;
    unsigned short* lA0 = As + w * 1024;        // wave-uniform LDS bases (elements)
    unsigned short* lA1 = As + w * 1024 + 512;
    unsigned short* lB0 = Bs + w * 1024;
    unsigned short* lB1 = Bs + w * 1024 + 512;

    f32x4 zero4 = {0.f, 0.f, 0.f, 0.f};
    f32x4 acc[4][4];
#pragma unroll
    for (int i = 0; i < 4; i++)
#pragma unroll
        for (int j = 0; j < 4; j++) acc[i][j] = zero4;

    for (int kt = 0; kt < 64; kt++) {
        int ko = kt * 32;
        __syncthreads();
        cp16(gA0 + ko, lA0);
        cp16(gA1 + ko, lA1);
        cp16(gB0 + ko, lB0);
        cp16(gB1 + ko, lB1);
        __syncthreads();

        bf16x8 aF[4], bF[4];
#pragma unroll
        for (int mt = 0; mt < 4; mt++)
            aF[mt] = *(const bf16x8*)(&As[(wm * 64 + mt * 16 + l15) * 32 + q * 8]);
#pragma unroll
        for (int nt = 0; nt < 4; nt++)
            bF[nt] = *(const bf16x8*)(&Bs[(wn * 64 + nt * 16 + l15) * 32 + q * 8]);
#pragma unroll
        for (int mt = 0; mt < 4; mt++)
#pragma unroll
            for (int nt = 0; nt < 4; nt++)
                acc[mt][nt] = __builtin_amdgcn_mfma_f32_16x16x32_bf16(aF[mt], bF[nt], acc[mt][nt], 0, 0, 0);
    }
#pragma unroll
    for (int nt = 0; nt < 4; nt++) {
        int n = nBase + wn * 64 + nt * 16 + l15;
        float bv = (n < 1024) ? bK[n] : bQ[n - 1024];
#pragma unroll
        for (int mt = 0; mt < 4; mt++)
#pragma unroll
            for (int r = 0; r < 4; r++) {
                int m = mBase + wm * 64 + mt * 16 + q * 4 + r;
                out[(size_t)m * 2048 + n] = f2bf(acc[mt][nt][r] + bv);
            }
    }
}

// ---------- kernel 5: fused attention per (b,h) ----------
// Transposed score matrix: Sm[j][i] = q_j.k_i/8 -> row softmax (contiguous),
// fin lands natively in PV A-operand layout. V staged to LDS coalesced.
__global__ __launch_bounds__(256) void k_attn(const unsigned short* __restrict__ kq,
                                              const unsigned short* __restrict__ abf,
                                              const unsigned short* __restrict__ lg,
                                              const float* __restrict__ wsp,
                                              const float* __restrict__ bsp,
                                              float* __restrict__ out) {
    __shared__ unsigned short shA[112 * 72 * 2];   // Ks|Qs, later fT[112][136]
    __shared__ unsigned short shB[128 * 128];      // Sm[112][102], later Vs[128][128]
    __shared__ float inv[112];
    unsigned short* Ks = shA;
    unsigned short* Qs = shA + 112 * 72;
    unsigned short* fT = shA;
    unsigned short* Sm = shB;
    unsigned short* Vs = shB;

    int h = blockIdx.x, b = blockIdx.y;
    int tid = threadIdx.x, lane = tid & 63, w = tid >> 6;
    int l15 = lane & 15, q = lane >> 4;

    // ---- stage K,Q (rows >= 100 zeroed) ----
    const unsigned short* Kg = kq + (size_t)(b * NSEQ) * 2048 + h * 64;
    const unsigned short* Qg = Kg + 1024;
    for (int c = tid; c < 112 * 8; c += 256) {
        int row = c >> 3, off = (c & 7) * 8;
        uint4 kv = {0, 0, 0, 0}, qv = {0, 0, 0, 0};
        if (row < NSEQ) {
            kv = *(const uint4*)(Kg + (size_t)row * 2048 + off);
            qv = *(const uint4*)(Qg + (size_t)row * 2048 + off);
        }
        *(uint4*)(&Ks[row * 72 + off]) = kv;
        *(uint4*)(&Qs[row * 72 + off]) = qv;
    }
    __syncthreads();

    // ---- Sm[j][i] = q_j . k_i / 8  (A=Q, B=K) ----
    for (int p = w; p < 49; p += 4) {
        int mt = p / 7, nt = p % 7;
        bf16x8 a0 = *(const bf16x8*)(&Qs[(mt * 16 + l15) * 72 + q * 8]);
        bf16x8 a1 = *(const bf16x8*)(&Qs[(mt * 16 + l15) * 72 + 32 + q * 8]);
        bf16x8 b0 = *(const bf16x8*)(&Ks[(nt * 16 + l15) * 72 + q * 8]);
        bf16x8 b1 = *(const bf16x8*)(&Ks[(nt * 16 + l15) * 72 + 32 + q * 8]);
        f32x4 c = {0.f, 0.f, 0.f, 0.f};
        c = __builtin_amdgcn_mfma_f32_16x16x32_bf16(a0, b0, c, 0, 0, 0);
        c = __builtin_amdgcn_mfma_f32_16x16x32_bf16(a1, b1, c, 0, 0, 0);
        int i = nt * 16 + l15;
        if (i < NSEQ) {
#pragma unroll
            for (int r = 0; r < 4; r++) {
                int j = mt * 16 + q * 4 + r;
                Sm[j * 102 + i] = f2bf(c[r] * 0.125f);
            }
        }
    }
    __syncthreads();

    // ---- row softmax over i, gate added from global (coalesced across threads) ----
    if (tid < 112) {
        int j = tid;
        unsigned short* Frow = fT + j * 136;
        if (j < NSEQ) {
            const unsigned short* Srow = Sm + j * 102;
            const unsigned short* lgc = lg + (size_t)h * GROWS + b * 10000 + j;
            float mx = -1e30f;
            for (int i = 0; i < NSEQ; i++) {
                float v = bf2f(Srow[i]) + bf2f(lgc[i * 100]);
                Frow[i] = f2bf(v);
                mx = fmaxf(mx, v);
            }
            float sum = 0.f;
            for (int i = 0; i < NSEQ; i++) {
                float e = __expf(bf2f(Frow[i]) - mx);
                sum += e;
                Frow[i] = f2bf(e);
            }
            for (int i = NSEQ; i < 128; i++) Frow[i] = 0;
            inv[j] = 1.f / sum;
        } else {
            for (int i = 0; i < 128; i++) Frow[i] = 0;
            inv[j] = 0.f;
        }
    }
    __syncthreads();

    // ---- stage V (overwrites Sm; rows >= 100 zeroed) ----
    const unsigned short* Vg = abf + (size_t)(b * NSEQ) * 2048 + h * 128;
    for (int c = tid; c < 128 * 16; c += 256) {
        int row = c >> 4, off = (c & 15) * 8;
        uint4 v = {0, 0, 0, 0};
        if (row < NSEQ) v = *(const uint4*)(Vg + (size_t)row * 2048 + off);
        *(uint4*)(&Vs[row * 128 + off]) = v;
    }
    __syncthreads();

    // ---- R = fin^T @ V; epilogue folds 1/sum, w_s, b_s ----
    float wsv = wsp[0], bsv = bsp[0];
    for (int nt2 = 0; nt2 < 2; nt2++) {
        int d0 = (w * 2 + nt2) * 16;
        bf16x8 bF[4];
#pragma unroll
        for (int ks = 0; ks < 4; ks++) {
            bf16x8 f;
#pragma unroll
            for (int jj = 0; jj < 8; jj++)
                f[jj] = (short)Vs[(ks * 32 + q * 8 + jj) * 128 + d0 + l15];
            bF[ks] = f;
        }
        for (int mt = 0; mt < 7; mt++) {
            f32x4 c = {0.f, 0.f, 0.f, 0.f};
#pragma unroll
            for (int ks = 0; ks < 4; ks++) {
                bf16x8 aF = *(const bf16x8*)(&fT[(mt * 16 + l15) * 136 + ks * 32 + q * 8]);
                c = __builtin_amdgcn_mfma_f32_16x16x32_bf16(aF, bF[ks], c, 0, 0, 0);
            }
#pragma unroll
            for (int r = 0; r < 4; r++) {
                int j = mt * 16 + q * 4 + r;
                if (j < NSEQ)
                    out[(size_t)(b * NSEQ + j) * 2048 + h * 128 + d0 + l15] = c[r] * inv[j] * wsv + bsv;
            }
        }
    }
}

// ---------- launch ----------
extern "C" void kernel_launch(void* const* d_in, const int* in_sizes, int n_in,
                              void* d_out, int out_size, void* d_ws, size_t ws_size,
                              hipStream_t stream) {
    const float* a  = (const float*)d_in[0];
    const float* g  = (const float*)d_in[1];
    const float* Wg = (const float*)d_in[4];
    const float* bg = (const float*)d_in[5];
    const float* WK = (const float*)d_in[6];
    const float* bK = (const float*)d_in[7];
    const float* WQ = (const float*)d_in[8];
    const float* bQ = (const float*)d_in[9];
    const float* ws_s = (const float*)d_in[10];
    const float* bs_s = (const float*)d_in[11];
    float* out = (float*)d_out;

    // workspace layout (bytes)
    const size_t off_abf = 0;                        // 6400*2048*2  = 26,214,400
    const size_t off_wt  = off_abf + 26214400;       // 2048*2048*2  =  8,388,608
    const size_t off_kq  = off_wt + 8388608;         // 6400*2048*2  = 26,214,400
    const size_t off_lg  = off_kq + 26214400;        // 16*640000*2  = 20,480,000
    const size_t need    = off_lg + 20480000;
    if (ws_size < need) return;

    char* ws = (char*)d_ws;
    unsigned short* a_bf = (unsigned short*)(ws + off_abf);
    unsigned short* Wt   = (unsigned short*)(ws + off_wt);
    unsigned short* kq   = (unsigned short*)(ws + off_kq);
    unsigned short* lg   = (unsigned short*)(ws + off_lg);

    k_cvt_a<<<12800, 256, 0, stream>>>(a, a_bf, 3276800);
    k_tw<<<dim3(32, 64, 2), 256, 0, stream>>>(WK, WQ, Wt);
    k_gate<<<10000, 256, 0, stream>>>(g, Wg, bg, lg);
    k_gemm<<<800, 256, 0, stream>>>(a_bf, Wt, bK, bQ, kq);
    k_attn<<<dim3(16, 64), 256, 0, stream>>>(kq, a_bf, lg, ws_s, bs_s, out);
}